// Round 2
// baseline (510.566 us; speedup 1.0000x reference)
//
#include <hip/hip_runtime.h>
#include <hip/hip_bf16.h>

typedef __attribute__((ext_vector_type(4))) float f32x4;
typedef __attribute__((ext_vector_type(8))) short s16x8;
typedef __attribute__((ext_vector_type(4))) short s16x4;

#define D_MODEL 1024
#define NH 16
#define HD 64
#define BB 4
#define TT 2048
#define MROWS (BB * TT) /* 8192 */
#define QSCALE 0.18033688011112042f /* 0.125 * log2(e): Q pre-scaled so softmax uses exp2 */

#define MFMA16(a, b, c) __builtin_amdgcn_mfma_f32_16x16x32_bf16(a, b, c, 0, 0, 0)
#define GLL16(g, l)                                                                   \
  __builtin_amdgcn_global_load_lds((const __attribute__((address_space(1))) void*)(g), \
                                   (__attribute__((address_space(3))) void*)(l), 16, 0, 0)

static __device__ __forceinline__ unsigned short f2bf(float f) {
  unsigned int u = __float_as_uint(f);
  u += 0x7fff + ((u >> 16) & 1);  // round-to-nearest-even
  return (unsigned short)(u >> 16);
}

// ---------------- fp32 -> bf16 convert (x) ----------------
__global__ void k_convert(const float* __restrict__ src, short* __restrict__ dst, int n4) {
  int i = blockIdx.x * blockDim.x + threadIdx.x;
  if (i >= n4) return;
  f32x4 v = reinterpret_cast<const f32x4*>(src)[i];
  s16x4 o;
#pragma unroll
  for (int r = 0; r < 4; r++) o[r] = (short)f2bf(v[r]);
  reinterpret_cast<s16x4*>(dst)[i] = o;
}

// ---------------- transpose + convert: W [K][N] fp32 -> Wt [N][K] bf16 ----------------
__global__ void k_transpose(const float* __restrict__ src, short* __restrict__ dst, int K, int N) {
  __shared__ float tile[32][33];
  int n0 = blockIdx.x * 32, k0 = blockIdx.y * 32;
  int tx = threadIdx.x, ty = threadIdx.y;  // (32, 8)
#pragma unroll
  for (int i = 0; i < 4; i++) tile[ty + i * 8][tx] = src[(size_t)(k0 + ty + i * 8) * N + n0 + tx];
  __syncthreads();
#pragma unroll
  for (int i = 0; i < 4; i++)
    dst[(size_t)(n0 + ty + i * 8) * K + k0 + tx] = (short)f2bf(tile[tx][ty + i * 8]);
}

// ---------------- GEMM: C[M,N] = A[M,K](bf16) @ Bt[N,K](bf16)^T + bias ----------------
// m97 structure: global_load_lds width-16 staging into linear [128][32] LDS, 2 barriers/K-step.
// MODE 0: qkv epilogue -> Q (pre-scaled by QSCALE) [BH][T][64], K [BH][T][64], V^T [BH][64][T]
// MODE 1: fp32 out [M][N]
template <int MODE>
__global__ void k_gemm(const short* __restrict__ A, const short* __restrict__ Bt,
                       const float* __restrict__ bias, int K, int N,
                       short* __restrict__ outQ, short* __restrict__ outK,
                       short* __restrict__ outV, float* __restrict__ outF) {
  __shared__ __align__(16) short lds_a[128 * 32];  // linear: required by global_load_lds
  __shared__ __align__(16) short lds_b[128 * 32];
  const int tid = threadIdx.x;
  const int m0 = blockIdx.y * 128, n0 = blockIdx.x * 128;
  const int w = tid >> 6, lane = tid & 63;
  const int wm = (w >> 1) * 64, wn = (w & 1) * 64;
  const int lr = lane & 15, lg = lane >> 4;

  // staging: wave w owns rows [w*32, w*32+32) of both tiles; 2 gll x 16 rows per matrix
  const short* aG = A + (size_t)(m0 + w * 32 + (lane >> 2)) * K + (lane & 3) * 8;
  const short* bG = Bt + (size_t)(n0 + w * 32 + (lane >> 2)) * K + (lane & 3) * 8;
  short* aL = &lds_a[(w * 32) * 32];
  short* bL = &lds_b[(w * 32) * 32];

  f32x4 acc[4][4] = {};

  for (int kt = 0; kt < K; kt += 32) {
    GLL16(aG + kt, aL);
    GLL16(aG + (size_t)16 * K + kt, aL + 16 * 32);
    GLL16(bG + kt, bL);
    GLL16(bG + (size_t)16 * K + kt, bL + 16 * 32);
    __syncthreads();  // drains vmcnt -> LDS tile ready
    s16x8 af[4], bfg[4];
#pragma unroll
    for (int i = 0; i < 4; i++) af[i] = *(const s16x8*)&lds_a[(wm + i * 16 + lr) * 32 + lg * 8];
#pragma unroll
    for (int j = 0; j < 4; j++) bfg[j] = *(const s16x8*)&lds_b[(wn + j * 16 + lr) * 32 + lg * 8];
#pragma unroll
    for (int i = 0; i < 4; i++) {
#pragma unroll
      for (int j = 0; j < 4; j++) acc[i][j] = MFMA16(af[i], bfg[j], acc[i][j]);
    }
    __syncthreads();  // protect LDS before next iteration's staging
  }

  // epilogue: D layout col = lane&15, row = 4*(lane>>4)+r (HW-verified)
#pragma unroll
  for (int j = 0; j < 4; j++) {
    const int ng = n0 + wn + j * 16 + lr;
    const float bv = bias[ng];
#pragma unroll
    for (int i = 0; i < 4; i++) {
      const int mg = m0 + wm + i * 16 + 4 * lg;  // rows mg..mg+3
      if (MODE == 0) {
        const int sec = ng >> 10, c = ng & 1023, h = c >> 6, d = c & 63;
        const int b = mg >> 11, t = mg & 2047;
        const int bh = b * NH + h;
        if (sec == 2) {  // V: transposed layout, 4 consecutive t -> one 8B store
          s16x4 pk;
#pragma unroll
          for (int r = 0; r < 4; r++) pk[r] = (short)f2bf(acc[i][j][r] + bv);
          *(s16x4*)&outV[((size_t)bh * HD + d) * TT + t] = pk;
        } else {
          short* dst = (sec == 0) ? outQ : outK;
          const float sc = (sec == 0) ? QSCALE : 1.0f;
#pragma unroll
          for (int r = 0; r < 4; r++)
            dst[((size_t)bh * TT + t + r) * HD + d] = (short)f2bf((acc[i][j][r] + bv) * sc);
        }
      } else {
#pragma unroll
        for (int r = 0; r < 4; r++) outF[(size_t)(mg + r) * N + ng] = acc[i][j][r] + bv;
      }
    }
  }
}

// ---------------- flash attention ----------------
// grid (T/128, B*H); 4 independent waves/block; each wave owns 32 q rows, KVBLK=64.
// Q pre-scaled by 0.125*log2e -> softmax in exp2 units, no per-element scale mul.
// S^T = mfma(K, Q) (D col = q = lane&15, row = kv). P -> per-wave LDS (packed b64
// writes) -> B-frag reads; both PV operands use the same LDS-mediated layout.
__global__ void k_attn(const short* __restrict__ Q, const short* __restrict__ Kb,
                       const short* __restrict__ Vt, short* __restrict__ Y) {
  __shared__ __align__(16) short plds[4][32 * 72];  // per-wave P tile [q=32][kv=64 pad 72]
  const int tid = threadIdx.x, w = tid >> 6, lane = tid & 63;
  const int lr = lane & 15, lg = lane >> 4;
  const int bh = blockIdx.y;
  const int qx = gridDim.x - 1 - blockIdx.x;  // reversed: heavy q-tiles dispatch first
  const int q0 = (qx * 4 + w) * 32;
  const int b = bh >> 4, h = bh & 15;
  const short* Qh = Q + (size_t)bh * TT * HD;
  const short* Kh = Kb + (size_t)bh * TT * HD;
  const short* Vh = Vt + (size_t)bh * HD * TT;
  short* pw = plds[w];

  s16x8 qf[2][2];  // [jq][kc]: B-frags, q = q0+jq*16+lr, k = kc*32+lg*8
#pragma unroll
  for (int jq = 0; jq < 2; jq++)
#pragma unroll
    for (int kc = 0; kc < 2; kc++)
      qf[jq][kc] = *(const s16x8*)&Qh[(q0 + jq * 16 + lr) * HD + kc * 32 + lg * 8];

  float mrow[2] = {-3e38f, -3e38f};
  float lrow[2] = {0.f, 0.f};
  f32x4 oacc[2][4] = {};  // y^T[d][q]: [jq][jd]

  const int kvend = q0 + 32;
  for (int kv0 = 0; kv0 < kvend; kv0 += 64) {
    // ---- all global loads batched up front (overlap with MFMA + softmax) ----
    s16x8 kf[4][2];
#pragma unroll
    for (int jk = 0; jk < 4; jk++) {
      int row = kv0 + jk * 16 + lr;
      row = min(row, TT - 1);  // clamp: duplicate rows are causally masked
      kf[jk][0] = *(const s16x8*)&Kh[row * HD + lg * 8];
      kf[jk][1] = *(const s16x8*)&Kh[row * HD + 32 + lg * 8];
    }
    s16x8 vf[2][4];
#pragma unroll
    for (int kc = 0; kc < 2; kc++) {
      int col = kv0 + kc * 32 + lg * 8;
      col = min(col, TT - 8);  // clamp: masked kv have p == 0
#pragma unroll
      for (int jd = 0; jd < 4; jd++) vf[kc][jd] = *(const s16x8*)&Vh[(jd * 16 + lr) * TT + col];
    }
    // ---- QK^T ----
    f32x4 s[4][2] = {};  // [jk][jq]
#pragma unroll
    for (int kc = 0; kc < 2; kc++)
#pragma unroll
      for (int jk = 0; jk < 4; jk++)
#pragma unroll
        for (int jq = 0; jq < 2; jq++) s[jk][jq] = MFMA16(kf[jk][kc], qf[jq][kc], s[jk][jq]);

    const bool diag = (kv0 + 63 > q0);  // wave-uniform: mask only near the diagonal
    // ---- online softmax (exp2 domain) ----
#pragma unroll
    for (int jq = 0; jq < 2; jq++) {
      const int qg = q0 + jq * 16 + lr;
      float mx = mrow[jq];
#pragma unroll
      for (int jk = 0; jk < 4; jk++) {
        if (diag) {
#pragma unroll
          for (int r = 0; r < 4; r++) {
            const int kvg = kv0 + jk * 16 + 4 * lg + r;
            if (kvg > qg) s[jk][jq][r] = -3e38f;
          }
        }
        mx = fmaxf(mx, fmaxf(fmaxf(s[jk][jq][0], s[jk][jq][1]), fmaxf(s[jk][jq][2], s[jk][jq][3])));
      }
      mx = fmaxf(mx, __shfl_xor(mx, 16));
      mx = fmaxf(mx, __shfl_xor(mx, 32));
      const float alpha = exp2f(mrow[jq] - mx);
      mrow[jq] = mx;
      float ps = 0.f;
#pragma unroll
      for (int jk = 0; jk < 4; jk++) {
        f32x4 p;
#pragma unroll
        for (int r = 0; r < 4; r++) {
          p[r] = exp2f(s[jk][jq][r] - mx);
          ps += p[r];
        }
        s16x4 pk;  // round-to-nearest bf16 (cheap +0x8000 variant), packed 8B store
#pragma unroll
        for (int r = 0; r < 4; r++) pk[r] = (short)((__float_as_uint(p[r]) + 0x8000) >> 16);
        *(s16x4*)&pw[(jq * 16 + lr) * 72 + jk * 16 + 4 * lg] = pk;
      }
      ps += __shfl_xor(ps, 16);
      ps += __shfl_xor(ps, 32);
      lrow[jq] = lrow[jq] * alpha + ps;
#pragma unroll
      for (int jd = 0; jd < 4; jd++) oacc[jq][jd] *= alpha;
    }
    // ---- PV: y^T[d][q] += Vt[d][kv] * P^T[kv][q] (same-wave DS ops are in-order) ----
#pragma unroll
    for (int kc = 0; kc < 2; kc++) {
#pragma unroll
      for (int jq = 0; jq < 2; jq++) {
        s16x8 pf = *(const s16x8*)&pw[(jq * 16 + lr) * 72 + kc * 32 + lg * 8];
#pragma unroll
        for (int jd = 0; jd < 4; jd++) oacc[jq][jd] = MFMA16(vf[kc][jd], pf, oacc[jq][jd]);
      }
    }
  }
  // epilogue: normalize, write Y [B][T][C] bf16; 4 consecutive d -> one 8B store
#pragma unroll
  for (int jq = 0; jq < 2; jq++) {
    const float inv = 1.0f / lrow[jq];
    const int t = q0 + jq * 16 + lr;
#pragma unroll
    for (int jd = 0; jd < 4; jd++) {
      s16x4 pk;
#pragma unroll
      for (int r = 0; r < 4; r++) pk[r] = (short)f2bf(oacc[jq][jd][r] * inv);
      *(s16x4*)&Y[((size_t)(b * TT + t)) * D_MODEL + h * HD + jd * 16 + 4 * lg] = pk;
    }
  }
}

extern "C" void kernel_launch(void* const* d_in, const int* in_sizes, int n_in,
                              void* d_out, int out_size, void* d_ws, size_t ws_size,
                              hipStream_t stream) {
  const float* x = (const float*)d_in[0];
  const float* Wqkv = (const float*)d_in[1];
  const float* bqkv = (const float*)d_in[2];
  const float* Wproj = (const float*)d_in[3];
  const float* bproj = (const float*)d_in[4];
  float* out = (float*)d_out;

  char* ws = (char*)d_ws;
  short* Xb = (short*)ws;                      // 16 MB  [8192][1024] bf16 (reused as Y)
  short* Wqkvt = (short*)(ws + (16u << 20));   // 6 MB   [3072][1024]
  short* Wprojt = (short*)(ws + (22u << 20));  // 2 MB   [1024][1024]
  short* Qb = (short*)(ws + (24u << 20));      // 16 MB  [64][2048][64] (pre-scaled)
  short* Kb = (short*)(ws + (40u << 20));      // 16 MB  [64][2048][64]
  short* Vtb = (short*)(ws + (56u << 20));     // 16 MB  [64][64][2048]  (V^T)
  short* Yb = Xb;                              // Xb dead after gemm_qkv

  k_convert<<<dim3(MROWS * D_MODEL / 4 / 256), 256, 0, stream>>>(x, Xb, MROWS * D_MODEL / 4);
  k_transpose<<<dim3(3 * D_MODEL / 32, D_MODEL / 32), dim3(32, 8), 0, stream>>>(
      Wqkv, Wqkvt, D_MODEL, 3 * D_MODEL);
  k_transpose<<<dim3(D_MODEL / 32, D_MODEL / 32), dim3(32, 8), 0, stream>>>(
      Wproj, Wprojt, D_MODEL, D_MODEL);
  k_gemm<0><<<dim3(3 * D_MODEL / 128, MROWS / 128), 256, 0, stream>>>(
      Xb, Wqkvt, bqkv, D_MODEL, 3 * D_MODEL, Qb, Kb, Vtb, nullptr);
  k_attn<<<dim3(TT / 128, BB * NH), 256, 0, stream>>>(Qb, Kb, Vtb, Yb);
  k_gemm<1><<<dim3(D_MODEL / 128, MROWS / 128), 256, 0, stream>>>(
      Yb, Wprojt, bproj, D_MODEL, D_MODEL, nullptr, nullptr, nullptr, out);
}

// Round 3
// 427.019 us; speedup vs baseline: 1.1957x; 1.1957x over previous
//
#include <hip/hip_runtime.h>
#include <hip/hip_bf16.h>

typedef __attribute__((ext_vector_type(4))) float f32x4;
typedef __attribute__((ext_vector_type(8))) short s16x8;
typedef __attribute__((ext_vector_type(4))) short s16x4;

#define D_MODEL 1024
#define NH 16
#define HD 64
#define BB 4
#define TT 2048
#define MROWS (BB * TT) /* 8192 */
#define QSCALE 0.18033688011112042f /* 0.125 * log2(e): Q pre-scaled so softmax uses exp2 */

#define MFMA16(a, b, c) __builtin_amdgcn_mfma_f32_16x16x32_bf16(a, b, c, 0, 0, 0)
#define GLL16(g, l)                                                                   \
  __builtin_amdgcn_global_load_lds((const __attribute__((address_space(1))) void*)(g), \
                                   (__attribute__((address_space(3))) void*)(l), 16, 0, 0)

static __device__ __forceinline__ unsigned short f2bf(float f) {
  unsigned int u = __float_as_uint(f);
  u += 0x7fff + ((u >> 16) & 1);  // round-to-nearest-even
  return (unsigned short)(u >> 16);
}

// ---------------- fp32 -> bf16 convert (x) ----------------
__global__ void k_convert(const float* __restrict__ src, short* __restrict__ dst, int n4) {
  int i = blockIdx.x * blockDim.x + threadIdx.x;
  if (i >= n4) return;
  f32x4 v = reinterpret_cast<const f32x4*>(src)[i];
  s16x4 o;
#pragma unroll
  for (int r = 0; r < 4; r++) o[r] = (short)f2bf(v[r]);
  reinterpret_cast<s16x4*>(dst)[i] = o;
}

// ---------------- transpose + convert: W [K][N] fp32 -> Wt [N][K] bf16 ----------------
__global__ void k_transpose(const float* __restrict__ src, short* __restrict__ dst, int K, int N) {
  __shared__ float tile[32][33];
  int n0 = blockIdx.x * 32, k0 = blockIdx.y * 32;
  int tx = threadIdx.x, ty = threadIdx.y;  // (32, 8)
#pragma unroll
  for (int i = 0; i < 4; i++) tile[ty + i * 8][tx] = src[(size_t)(k0 + ty + i * 8) * N + n0 + tx];
  __syncthreads();
#pragma unroll
  for (int i = 0; i < 4; i++)
    dst[(size_t)(n0 + ty + i * 8) * K + k0 + tx] = (short)f2bf(tile[tx][ty + i * 8]);
}

// ---------------- GEMM: C[M,N] = A[M,K](bf16) @ Bt[N,K](bf16)^T + bias ----------------
// m97 structure: global_load_lds width-16 staging into linear [128][32] LDS, 2 barriers/K-step.
// MODE 0: qkv epilogue -> Q (pre-scaled by QSCALE) [BH][T][64], K [BH][T][64], V^T [BH][64][T]
// MODE 1: fp32 out [M][N]
template <int MODE>
__global__ __launch_bounds__(256, 2) void k_gemm(
    const short* __restrict__ A, const short* __restrict__ Bt, const float* __restrict__ bias,
    int K, int N, short* __restrict__ outQ, short* __restrict__ outK, short* __restrict__ outV,
    float* __restrict__ outF) {
  __shared__ __align__(16) short lds_a[128 * 32];  // linear: required by global_load_lds
  __shared__ __align__(16) short lds_b[128 * 32];
  const int tid = threadIdx.x;
  const int m0 = blockIdx.y * 128, n0 = blockIdx.x * 128;
  const int w = tid >> 6, lane = tid & 63;
  const int wm = (w >> 1) * 64, wn = (w & 1) * 64;
  const int lr = lane & 15, lg = lane >> 4;

  // staging: wave w owns rows [w*32, w*32+32) of both tiles; 2 gll x 16 rows per matrix
  const short* aG = A + (size_t)(m0 + w * 32 + (lane >> 2)) * K + (lane & 3) * 8;
  const short* bG = Bt + (size_t)(n0 + w * 32 + (lane >> 2)) * K + (lane & 3) * 8;
  short* aL = &lds_a[(w * 32) * 32];
  short* bL = &lds_b[(w * 32) * 32];

  f32x4 acc[4][4] = {};

  for (int kt = 0; kt < K; kt += 32) {
    GLL16(aG + kt, aL);
    GLL16(aG + (size_t)16 * K + kt, aL + 16 * 32);
    GLL16(bG + kt, bL);
    GLL16(bG + (size_t)16 * K + kt, bL + 16 * 32);
    __syncthreads();  // drains vmcnt -> LDS tile ready
    s16x8 af[4], bfg[4];
#pragma unroll
    for (int i = 0; i < 4; i++) af[i] = *(const s16x8*)&lds_a[(wm + i * 16 + lr) * 32 + lg * 8];
#pragma unroll
    for (int j = 0; j < 4; j++) bfg[j] = *(const s16x8*)&lds_b[(wn + j * 16 + lr) * 32 + lg * 8];
#pragma unroll
    for (int i = 0; i < 4; i++) {
#pragma unroll
      for (int j = 0; j < 4; j++) acc[i][j] = MFMA16(af[i], bfg[j], acc[i][j]);
    }
    __syncthreads();  // protect LDS before next iteration's staging
  }

  // epilogue: D layout col = lane&15, row = 4*(lane>>4)+r (HW-verified)
#pragma unroll
  for (int j = 0; j < 4; j++) {
    const int ng = n0 + wn + j * 16 + lr;
    const float bv = bias[ng];
#pragma unroll
    for (int i = 0; i < 4; i++) {
      const int mg = m0 + wm + i * 16 + 4 * lg;  // rows mg..mg+3
      if (MODE == 0) {
        const int sec = ng >> 10, c = ng & 1023, h = c >> 6, d = c & 63;
        const int b = mg >> 11, t = mg & 2047;
        const int bh = b * NH + h;
        if (sec == 2) {  // V: transposed layout, 4 consecutive t -> one 8B store
          s16x4 pk;
#pragma unroll
          for (int r = 0; r < 4; r++) pk[r] = (short)f2bf(acc[i][j][r] + bv);
          *(s16x4*)&outV[((size_t)bh * HD + d) * TT + t] = pk;
        } else {
          short* dst = (sec == 0) ? outQ : outK;
          const float sc = (sec == 0) ? QSCALE : 1.0f;
#pragma unroll
          for (int r = 0; r < 4; r++)
            dst[((size_t)bh * TT + t + r) * HD + d] = (short)f2bf((acc[i][j][r] + bv) * sc);
        }
      } else {
#pragma unroll
        for (int r = 0; r < 4; r++) outF[(size_t)(mg + r) * N + ng] = acc[i][j][r] + bv;
      }
    }
  }
}

// ---------------- flash attention ----------------
// grid (T/128, B*H); 4 independent waves/block; each wave owns 32 q rows, KVBLK=64.
// __launch_bounds__(256,2): 256-reg unified budget -> batched K/V loads stay in
// registers (round-2 regression: default bounds capped at ~128 -> 184 MB scratch spill).
__global__ __launch_bounds__(256, 2) void k_attn(const short* __restrict__ Q,
                                                 const short* __restrict__ Kb,
                                                 const short* __restrict__ Vt,
                                                 short* __restrict__ Y) {
  __shared__ __align__(16) short plds[4][32 * 72];  // per-wave P tile [q=32][kv=64 pad 72]
  const int tid = threadIdx.x, w = tid >> 6, lane = tid & 63;
  const int lr = lane & 15, lg = lane >> 4;
  const int bh = blockIdx.y;
  const int qx = gridDim.x - 1 - blockIdx.x;  // reversed: heavy q-tiles dispatch first
  const int q0 = (qx * 4 + w) * 32;
  const int b = bh >> 4, h = bh & 15;
  const short* Qh = Q + (size_t)bh * TT * HD;
  const short* Kh = Kb + (size_t)bh * TT * HD;
  const short* Vh = Vt + (size_t)bh * HD * TT;
  short* pw = plds[w];

  s16x8 qf[2][2];  // [jq][kc]: B-frags, q = q0+jq*16+lr, k = kc*32+lg*8
#pragma unroll
  for (int jq = 0; jq < 2; jq++)
#pragma unroll
    for (int kc = 0; kc < 2; kc++)
      qf[jq][kc] = *(const s16x8*)&Qh[(q0 + jq * 16 + lr) * HD + kc * 32 + lg * 8];

  float mrow[2] = {-3e38f, -3e38f};
  float lrow[2] = {0.f, 0.f};
  f32x4 oacc[2][4] = {};  // y^T[d][q]: [jq][jd]

  const int kvend = q0 + 32;
  for (int kv0 = 0; kv0 < kvend; kv0 += 64) {
    // ---- all global loads batched up front (overlap with MFMA + softmax) ----
    s16x8 kf[4][2];
#pragma unroll
    for (int jk = 0; jk < 4; jk++) {
      int row = kv0 + jk * 16 + lr;
      row = min(row, TT - 1);  // clamp: duplicate rows are causally masked
      kf[jk][0] = *(const s16x8*)&Kh[row * HD + lg * 8];
      kf[jk][1] = *(const s16x8*)&Kh[row * HD + 32 + lg * 8];
    }
    s16x8 vf[2][4];
#pragma unroll
    for (int kc = 0; kc < 2; kc++) {
      int col = kv0 + kc * 32 + lg * 8;
      col = min(col, TT - 8);  // clamp: masked kv have p == 0
#pragma unroll
      for (int jd = 0; jd < 4; jd++) vf[kc][jd] = *(const s16x8*)&Vh[(jd * 16 + lr) * TT + col];
    }
    // ---- QK^T ----
    f32x4 s[4][2] = {};  // [jk][jq]
#pragma unroll
    for (int kc = 0; kc < 2; kc++)
#pragma unroll
      for (int jk = 0; jk < 4; jk++)
#pragma unroll
        for (int jq = 0; jq < 2; jq++) s[jk][jq] = MFMA16(kf[jk][kc], qf[jq][kc], s[jk][jq]);

    const bool diag = (kv0 + 63 > q0);  // wave-uniform: mask only near the diagonal
    // ---- online softmax (exp2 domain) ----
#pragma unroll
    for (int jq = 0; jq < 2; jq++) {
      const int qg = q0 + jq * 16 + lr;
      float mx = mrow[jq];
#pragma unroll
      for (int jk = 0; jk < 4; jk++) {
        if (diag) {
#pragma unroll
          for (int r = 0; r < 4; r++) {
            const int kvg = kv0 + jk * 16 + 4 * lg + r;
            if (kvg > qg) s[jk][jq][r] = -3e38f;
          }
        }
        mx = fmaxf(mx, fmaxf(fmaxf(s[jk][jq][0], s[jk][jq][1]), fmaxf(s[jk][jq][2], s[jk][jq][3])));
      }
      mx = fmaxf(mx, __shfl_xor(mx, 16));
      mx = fmaxf(mx, __shfl_xor(mx, 32));
      const float alpha = exp2f(mrow[jq] - mx);
      mrow[jq] = mx;
      float ps = 0.f;
#pragma unroll
      for (int jk = 0; jk < 4; jk++) {
        f32x4 p;
#pragma unroll
        for (int r = 0; r < 4; r++) {
          p[r] = exp2f(s[jk][jq][r] - mx);
          ps += p[r];
        }
        s16x4 pk;  // round-to-nearest bf16 (cheap +0x8000 variant), packed 8B store
#pragma unroll
        for (int r = 0; r < 4; r++) pk[r] = (short)((__float_as_uint(p[r]) + 0x8000) >> 16);
        *(s16x4*)&pw[(jq * 16 + lr) * 72 + jk * 16 + 4 * lg] = pk;
      }
      ps += __shfl_xor(ps, 16);
      ps += __shfl_xor(ps, 32);
      lrow[jq] = lrow[jq] * alpha + ps;
#pragma unroll
      for (int jd = 0; jd < 4; jd++) oacc[jq][jd] *= alpha;
    }
    // ---- PV: y^T[d][q] += Vt[d][kv] * P^T[kv][q] (same-wave DS ops are in-order) ----
#pragma unroll
    for (int kc = 0; kc < 2; kc++) {
#pragma unroll
      for (int jq = 0; jq < 2; jq++) {
        s16x8 pf = *(const s16x8*)&pw[(jq * 16 + lr) * 72 + kc * 32 + lg * 8];
#pragma unroll
        for (int jd = 0; jd < 4; jd++) oacc[jq][jd] = MFMA16(vf[kc][jd], pf, oacc[jq][jd]);
      }
    }
  }
  // epilogue: normalize, write Y [B][T][C] bf16; 4 consecutive d -> one 8B store
#pragma unroll
  for (int jq = 0; jq < 2; jq++) {
    const float inv = 1.0f / lrow[jq];
    const int t = q0 + jq * 16 + lr;
#pragma unroll
    for (int jd = 0; jd < 4; jd++) {
      s16x4 pk;
#pragma unroll
      for (int r = 0; r < 4; r++) pk[r] = (short)f2bf(oacc[jq][jd][r] * inv);
      *(s16x4*)&Y[((size_t)(b * TT + t)) * D_MODEL + h * HD + jd * 16 + 4 * lg] = pk;
    }
  }
}

extern "C" void kernel_launch(void* const* d_in, const int* in_sizes, int n_in,
                              void* d_out, int out_size, void* d_ws, size_t ws_size,
                              hipStream_t stream) {
  const float* x = (const float*)d_in[0];
  const float* Wqkv = (const float*)d_in[1];
  const float* bqkv = (const float*)d_in[2];
  const float* Wproj = (const float*)d_in[3];
  const float* bproj = (const float*)d_in[4];
  float* out = (float*)d_out;

  char* ws = (char*)d_ws;
  short* Xb = (short*)ws;                      // 16 MB  [8192][1024] bf16 (reused as Y)
  short* Wqkvt = (short*)(ws + (16u << 20));   // 6 MB   [3072][1024]
  short* Wprojt = (short*)(ws + (22u << 20));  // 2 MB   [1024][1024]
  short* Qb = (short*)(ws + (24u << 20));      // 16 MB  [64][2048][64] (pre-scaled)
  short* Kb = (short*)(ws + (40u << 20));      // 16 MB  [64][2048][64]
  short* Vtb = (short*)(ws + (56u << 20));     // 16 MB  [64][64][2048]  (V^T)
  short* Yb = Xb;                              // Xb dead after gemm_qkv

  k_convert<<<dim3(MROWS * D_MODEL / 4 / 256), 256, 0, stream>>>(x, Xb, MROWS * D_MODEL / 4);
  k_transpose<<<dim3(3 * D_MODEL / 32, D_MODEL / 32), dim3(32, 8), 0, stream>>>(
      Wqkv, Wqkvt, D_MODEL, 3 * D_MODEL);
  k_transpose<<<dim3(D_MODEL / 32, D_MODEL / 32), dim3(32, 8), 0, stream>>>(
      Wproj, Wprojt, D_MODEL, D_MODEL);
  k_gemm<0><<<dim3(3 * D_MODEL / 128, MROWS / 128), 256, 0, stream>>>(
      Xb, Wqkvt, bqkv, D_MODEL, 3 * D_MODEL, Qb, Kb, Vtb, nullptr);
  k_attn<<<dim3(TT / 128, BB * NH), 256, 0, stream>>>(Qb, Kb, Vtb, Yb);
  k_gemm<1><<<dim3(D_MODEL / 128, MROWS / 128), 256, 0, stream>>>(
      Yb, Wprojt, bproj, D_MODEL, D_MODEL, nullptr, nullptr, nullptr, out);
}